// Round 14
// baseline (61.400 us; speedup 1.0000x reference)
//
#include <hip/hip_runtime.h>
#include <hip/hip_bf16.h>
#include <math.h>

// Problem constants
#define BB 64
#define SS 2048
#define HH 1024
#define EE 1024
#define DD 64          // window half-size
#define G4H 4096       // 4*H
#define KS1 8          // k-splits gates GEMM (K=3072, kchunk=384) -> grid (128,8)=1024 blocks
#define KS2 8          // k-splits H=1024 GEMMs (kchunk=128)      -> grid (32,8)=256 blocks

typedef __attribute__((ext_vector_type(8))) short short8;
typedef __attribute__((ext_vector_type(4))) float floatx4;

#define MFMA_BF16(a, b, c) __builtin_amdgcn_mfma_f32_16x16x32_bf16((a), (b), (c), 0, 0, 0)

__device__ __forceinline__ float sigmoidf_(float x) { return 1.0f / (1.0f + expf(-x)); }

__device__ __forceinline__ ushort f2bf(float f) {
    return __builtin_bit_cast(ushort, __float2bfloat16(f));
}

// Truncation-based hi/lo bf16 split of a float4, stored to LDS (row stride 72 ushorts).
// hi = top 16 bits (bit-ops only); lo = (v - hi) rounded to bf16.
__device__ __forceinline__ void stage_split(ushort* hbase, ushort* lbase, int row, int col, float4 v) {
    const uint bx = __float_as_uint(v.x), by = __float_as_uint(v.y);
    const uint bz = __float_as_uint(v.z), bw = __float_as_uint(v.w);
    uint2 hp;
    hp.x = (bx >> 16) | (by & 0xffff0000u);
    hp.y = (bz >> 16) | (bw & 0xffff0000u);
    const float lx = v.x - __uint_as_float(bx & 0xffff0000u);
    const float ly = v.y - __uint_as_float(by & 0xffff0000u);
    const float lz = v.z - __uint_as_float(bz & 0xffff0000u);
    const float lw = v.w - __uint_as_float(bw & 0xffff0000u);
    uint2 lp;
    lp.x = (uint)f2bf(lx) | ((uint)f2bf(ly) << 16);
    lp.y = (uint)f2bf(lz) | ((uint)f2bf(lw) << 16);
    *(uint2*)(hbase + row * 72 + col) = hp;
    *(uint2*)(lbase + row * 72 + col) = lp;
}

// bf16x3 split-MFMA partial GEMM, j-tile 32: part = sum_{k in chunk} Xrow(b,k)*Wrow(j,k)
// X/W are concats of two row-major matrices along k (split at k1len).
// Tile: 32 j x 64 b x 64 k. 4 waves: wave w -> j-subtile (w&1), b-subtiles {2*(w>>1), 2*(w>>1)+1}.
// grid=(Jtot/32, KS), block=256. LDS 27.6 KB.
// STORE_BJ=false: part[ks][j][b] (scalar). STORE_BJ=true: part[ks][b][j] (float4).
template<bool STORE_BJ>
__global__ __launch_bounds__(256) void gemm_mfma32(
    const float* __restrict__ X1, int x1ld,
    const float* __restrict__ X2, int x2ld,
    const float* __restrict__ W1, int w1ld,
    const float* __restrict__ W2, int w2ld,
    int k1len, int Ktot, int Jtot,
    float* __restrict__ part)
{
    const int jt = blockIdx.x;        // j-tile of 32
    const int ks = blockIdx.y;
    const int KS = gridDim.y;
    const int kchunk = Ktot / KS;
    const int k0 = ks * kchunk;
    const int t  = threadIdx.x;

    const int c = t & 15;             // staging k-col group (4 floats)
    const int r = t >> 4;             // staging row group (0..15)
    const int lane = t & 63;
    const int w    = t >> 6;
    const int wjs  = w & 1;           // j-subtile (0..1)
    const int wbs  = w >> 1;          // b-pair (0..1) -> b-subtiles 2*wbs, 2*wbs+1
    const int rr   = lane & 15;
    const int kg   = lane >> 4;

    __shared__ __align__(16) ushort Wh[32][72];
    __shared__ __align__(16) ushort Wl[32][72];
    __shared__ __align__(16) ushort Xh[64][72];
    __shared__ __align__(16) ushort Xl[64][72];

    floatx4 acc[2];
    acc[0] = (floatx4){0.f, 0.f, 0.f, 0.f};
    acc[1] = (floatx4){0.f, 0.f, 0.f, 0.f};

    for (int kk = k0; kk < k0 + kchunk; kk += 64) {
        const int kg4 = kk + 4 * c;
        // stage X: 64 rows (4 per thread)
#pragma unroll
        for (int i = 0; i < 4; ++i) {
            const int row = r + 16 * i;
            const float* xs = (kg4 < k1len) ? (X1 + (size_t)row * x1ld + kg4)
                                            : (X2 + (size_t)row * x2ld + (kg4 - k1len));
            stage_split(&Xh[0][0], &Xl[0][0], row, 4 * c, *(const float4*)xs);
        }
        // stage W: 32 rows (2 per thread)
#pragma unroll
        for (int i = 0; i < 2; ++i) {
            const int row = r + 16 * i;
            const int j = jt * 32 + row;
            const float* wsrc = (kg4 < k1len) ? (W1 + (size_t)j * w1ld + kg4)
                                              : (W2 + (size_t)j * w2ld + (kg4 - k1len));
            stage_split(&Wh[0][0], &Wl[0][0], row, 4 * c, *(const float4*)wsrc);
        }
        __syncthreads();

        const int aoff = (wjs * 16 + rr) * 72 + kg * 8;
        short8 ah[2], al[2];
        ah[0] = *(const short8*)((const void*)(&Wh[0][0] + aoff));
        ah[1] = *(const short8*)((const void*)(&Wh[0][0] + aoff + 32));
        al[0] = *(const short8*)((const void*)(&Wl[0][0] + aoff));
        al[1] = *(const short8*)((const void*)(&Wl[0][0] + aoff + 32));

#pragma unroll
        for (int i = 0; i < 2; ++i) {
            const int bs = wbs * 2 + i;
            const int boff = (bs * 16 + rr) * 72 + kg * 8;
#pragma unroll
            for (int kh = 0; kh < 2; ++kh) {
                short8 bh = *(const short8*)((const void*)(&Xh[0][0] + boff + kh * 32));
                short8 bl = *(const short8*)((const void*)(&Xl[0][0] + boff + kh * 32));
                acc[i] = MFMA_BF16(ah[kh], bh, acc[i]);   // hi*hi
                acc[i] = MFMA_BF16(al[kh], bh, acc[i]);   // lo*hi
                acc[i] = MFMA_BF16(ah[kh], bl, acc[i]);   // hi*lo
            }
        }
        __syncthreads();
    }

    // C/D layout: col = rr (b within subtile), row = kg*4 + reg (j within subtile)
    if (STORE_BJ) {
        const int j0 = jt * 32 + wjs * 16 + kg * 4;
#pragma unroll
        for (int i = 0; i < 2; ++i) {
            const int b = (wbs * 2 + i) * 16 + rr;
            *(float4*)&part[((size_t)ks * BB + b) * Jtot + j0] =
                (float4){acc[i][0], acc[i][1], acc[i][2], acc[i][3]};
        }
    } else {
#pragma unroll
        for (int i = 0; i < 2; ++i) {
            const int b = (wbs * 2 + i) * 16 + rr;
#pragma unroll
            for (int reg = 0; reg < 4; ++reg) {
                const int j = jt * 32 + wjs * 16 + kg * 4 + reg;
                part[((size_t)ks * Jtot + j) * BB + b] = acc[i][reg];
            }
        }
    }
}

// LSTM cell from gate partials (layout [ks][j][b]). grid = H/4 = 256 blocks, block = 256.
__global__ __launch_bounds__(256) void lstm_cell(
    const float* __restrict__ part,
    const float* __restrict__ b_ih, const float* __restrict__ b_hh,
    const float* __restrict__ c0, float* __restrict__ yt)
{
    const int t = threadIdx.x;
    const int b = t & 63;
    const int h = blockIdx.x * 4 + (t >> 6);

    float g4[4];
#pragma unroll
    for (int q = 0; q < 4; ++q) {
        const int j = h + q * HH;
        float s = b_ih[j] + b_hh[j];
#pragma unroll
        for (int ks = 0; ks < KS1; ++ks)
            s += part[((size_t)ks * G4H + j) * BB + b];
        g4[q] = s;
    }
    const float ig = sigmoidf_(g4[0]);
    const float fg = sigmoidf_(g4[1]);
    const float gg = tanhf(g4[2]);
    const float og = sigmoidf_(g4[3]);
    const float c  = fg * c0[(size_t)b * HH + h] + ig * gg;
    yt[(size_t)b * HH + h] = og * tanhf(c);
}

// p_t = len * sigmoid( sum_i tanh(t1[b][i]) * v[i] ); window bounds.
// part2 layout [ks][b][i] -> coalesced float4 reads. grid = B, block = 256.
__global__ __launch_bounds__(256) void pos_kernel(
    const float* __restrict__ part2, const float* __restrict__ v,
    const int* __restrict__ elen,
    float* __restrict__ p_out, int* __restrict__ lr_out)
{
    const int b = blockIdx.x;
    const int t = threadIdx.x;

    float4 s = {0.f, 0.f, 0.f, 0.f};
#pragma unroll
    for (int ks = 0; ks < KS2; ++ks) {
        float4 pv = *(const float4*)&part2[((size_t)ks * BB + b) * HH + t * 4];
        s.x += pv.x; s.y += pv.y; s.z += pv.z; s.w += pv.w;
    }
    const float4 vv = *(const float4*)&v[t * 4];
    float acc = tanhf(s.x) * vv.x + tanhf(s.y) * vv.y
              + tanhf(s.z) * vv.z + tanhf(s.w) * vv.w;

    __shared__ float red[256];
    red[t] = acc;
    __syncthreads();
    if (t < 128) red[t] += red[t + 128];
    __syncthreads();
    if (t < 64) {
        float x = red[t] + red[t + 64];
#pragma unroll
        for (int off = 32; off; off >>= 1) x += __shfl_xor(x, off);
        if (t == 0) {
            const float pt  = sigmoidf_(x);
            const float len = (float)elen[b];
            const float p   = len * pt;
            const int   pf  = (int)floorf(p);
            const int   left  = max(0, pf - DD);
            const int   right = min(elen[b], pf + DD);
            p_out[b] = p;
            lr_out[b * 2 + 0] = left;
            lr_out[b * 2 + 1] = right;
        }
    }
}

// Windowed raw scores. grid = (B, 16), block = 256 (4 waves, 2 si each).
// Writes sc[b][0..128) with -1e30 padding beyond window.
__global__ __launch_bounds__(256) void attn_scores(
    const float* __restrict__ encode_h, const float* __restrict__ yt,
    const int* __restrict__ lr, float* __restrict__ sc_out)
{
    const int b = blockIdx.x;
    const int q = blockIdx.y;
    const int t = threadIdx.x;
    const int lane = t & 63;
    const int wv = t >> 6;

    __shared__ float yts[HH];
    *(float4*)&yts[t * 4] = *(const float4*)&yt[(size_t)b * HH + t * 4];
    const int left = lr[b * 2], right = lr[b * 2 + 1];
    const int wsize = right - left;
    __syncthreads();

#pragma unroll
    for (int rr = 0; rr < 2; ++rr) {
        const int si = q * 8 + wv * 2 + rr;
        float s = -1e30f;
        if (si < wsize) {
            const float* eh = encode_h + ((size_t)b * SS + (left + si)) * HH;
            s = 0.0f;
#pragma unroll
            for (int cc = 0; cc < 4; ++cc) {
                const int hb = cc * 256 + lane * 4;
                float4 e = *(const float4*)(eh + hb);
                s += e.x * yts[hb] + e.y * yts[hb + 1] + e.z * yts[hb + 2] + e.w * yts[hb + 3];
            }
#pragma unroll
            for (int off = 32; off; off >>= 1) s += __shfl_xor(s, off);
        }
        if (lane == 0) sc_out[b * 2 * DD + si] = s;
    }
}

// Fused softmax+gauss+ct: grid = (B, 8), block = 512 = 4 si-quarters x 128 h.
__global__ __launch_bounds__(512) void attn_ct(
    const float* __restrict__ encode_h, const float* __restrict__ sc,
    const float* __restrict__ p_buf, const int* __restrict__ lr,
    float* __restrict__ ct)
{
    const int b = blockIdx.x;
    const int t = threadIdx.x;
    const int lane = t & 63;
    const int hh = t & 127;          // h within 128-chunk
    const int q  = t >> 7;           // si-quarter 0..3
    const int h = blockIdx.y * 128 + hh;

    __shared__ float scs[2 * DD];
    __shared__ float ats[2 * DD];
    __shared__ float red[4][128];

    const int left = lr[b * 2];
    if (t < 2 * DD) scs[t] = sc[b * 2 * DD + t];
    __syncthreads();

    float m = fmaxf(scs[lane], scs[lane + 64]);
#pragma unroll
    for (int off = 32; off; off >>= 1) m = fmaxf(m, __shfl_xor(m, off));
    float ssum = expf(scs[lane] - m) + expf(scs[lane + 64] - m);
#pragma unroll
    for (int off = 32; off; off >>= 1) ssum += __shfl_xor(ssum, off);
    const float inv = 1.0f / ssum;

    if (t < 2 * DD) {
        const float dj = (float)(left + t) - p_buf[b];
        ats[t] = expf(scs[t] - m) * inv * expf(-(dj * dj) * (1.0f / 2048.0f));
    }
    __syncthreads();

    const float* ehb = encode_h + ((size_t)b * SS + left + q * 32) * HH + h;
    const float* atp = &ats[q * 32];
    float a0 = 0, a1 = 0, a2 = 0, a3 = 0, a4 = 0, a5 = 0, a6 = 0, a7 = 0;
#pragma unroll
    for (int si = 0; si < 32; si += 8) {
        a0 = fmaf(atp[si + 0], ehb[(size_t)(si + 0) * HH], a0);
        a1 = fmaf(atp[si + 1], ehb[(size_t)(si + 1) * HH], a1);
        a2 = fmaf(atp[si + 2], ehb[(size_t)(si + 2) * HH], a2);
        a3 = fmaf(atp[si + 3], ehb[(size_t)(si + 3) * HH], a3);
        a4 = fmaf(atp[si + 4], ehb[(size_t)(si + 4) * HH], a4);
        a5 = fmaf(atp[si + 5], ehb[(size_t)(si + 5) * HH], a5);
        a6 = fmaf(atp[si + 6], ehb[(size_t)(si + 6) * HH], a6);
        a7 = fmaf(atp[si + 7], ehb[(size_t)(si + 7) * HH], a7);
    }
    const float a = ((a0 + a1) + (a2 + a3)) + ((a4 + a5) + (a6 + a7));

    if (q != 0) red[q][hh] = a;
    __syncthreads();
    if (q == 0)
        ct[(size_t)b * HH + h] = (a + red[1][hh]) + (red[2][hh] + red[3][hh]);
}

// out[b][j] = sum_ks part3[ks][j][b].  grid = H/4 = 256, block = 256 (coalesced reads).
__global__ __launch_bounds__(256) void reduce_out(
    const float* __restrict__ part3, float* __restrict__ out)
{
    const int t = threadIdx.x;
    const int b = t & 63;
    const int j = blockIdx.x * 4 + (t >> 6);
    float s = 0.0f;
#pragma unroll
    for (int ks = 0; ks < KS2; ++ks)
        s += part3[((size_t)ks * HH + j) * BB + b];
    out[(size_t)b * HH + j] = s;
}

extern "C" void kernel_launch(void* const* d_in, const int* in_sizes, int n_in,
                              void* d_out, int out_size, void* d_ws, size_t ws_size,
                              hipStream_t stream)
{
    const float* encode_h = (const float*)d_in[0];
    const float* x_t      = (const float*)d_in[1];
    const float* h0       = (const float*)d_in[2];
    const float* c0       = (const float*)d_in[3];
    const float* W_ih     = (const float*)d_in[4];
    const float* W_hh     = (const float*)d_in[5];
    const float* b_ih     = (const float*)d_in[6];
    const float* b_hh     = (const float*)d_in[7];
    const float* W_ht2tan = (const float*)d_in[8];
    const float* W_tan2pt = (const float*)d_in[9];
    const float* W_ct2ht  = (const float*)d_in[10];
    const int*   elen     = (const int*)d_in[11];
    float* out = (float*)d_out;

    float* ws = (float*)d_ws;
    float* gates_part = ws;                                   // KS1*4096*64 = 2M floats
    float* yt    = gates_part + (size_t)KS1 * G4H * BB;       // 65536
    float* part2 = yt + (size_t)BB * HH;                      // KS2*1024*64 = 512K
    float* pbuf  = part2 + (size_t)KS2 * HH * BB;             // 64
    int*   lrbuf = (int*)(pbuf + BB);                         // 128 ints
    float* scbuf = pbuf + BB + 2 * BB;                        // 64*128
    float* ctbuf = scbuf + (size_t)BB * 2 * DD;               // 65536
    float* part3 = ctbuf + (size_t)BB * HH;                   // KS2*1024*64 = 512K

    // K1: gates partial GEMM (K = 2048 | 1024 concat), grid (128,8) = 1024 blocks (4/CU)
    dim3 g1(G4H / 32, KS1);
    gemm_mfma32<false><<<g1, 256, 0, stream>>>(x_t, EE + HH, h0, HH,
                                               W_ih, EE + HH, W_hh, HH,
                                               2048, 3072, G4H, gates_part);
    // K2: LSTM cell -> yt
    lstm_cell<<<HH / 4, 256, 0, stream>>>(gates_part, b_ih, b_hh, c0, yt);

    // K3a: t1 = yt @ W_ht2tan^T (partials, [ks][b][j] layout), grid (32,8) = 256 blocks
    dim3 g3(HH / 32, KS2);
    gemm_mfma32<true><<<g3, 256, 0, stream>>>(yt, HH, yt, HH,
                                              W_ht2tan, HH, W_ht2tan, HH,
                                              HH, HH, HH, part2);
    // K3b: p, window bounds (coalesced float4 reads of part2)
    pos_kernel<<<BB, 256, 0, stream>>>(part2, W_tan2pt, elen, pbuf, lrbuf);

    // K4a: windowed raw scores, grid (64,16) = 1024 blocks (2 si per wave)
    dim3 g4a(BB, 16);
    attn_scores<<<g4a, 256, 0, stream>>>(encode_h, yt, lrbuf, scbuf);
    // K4b: softmax + gauss + ct, grid (64,8) = 512 blocks, block 512
    dim3 g4b(BB, 8);
    attn_ct<<<g4b, 512, 0, stream>>>(encode_h, scbuf, pbuf, lrbuf, ctbuf);

    // K5: ht partials = ct @ W_ct2ht^T, grid (32,8), [ks][j][b] layout
    gemm_mfma32<false><<<g3, 256, 0, stream>>>(ctbuf, HH, ctbuf, HH,
                                               W_ct2ht, HH, W_ct2ht, HH,
                                               HH, HH, HH, part3);
    // K6: reduce -> out
    reduce_out<<<HH / 4, 256, 0, stream>>>(part3, out);
}

// Round 15
// 55.019 us; speedup vs baseline: 1.1160x; 1.1160x over previous
//
#include <hip/hip_runtime.h>
#include <hip/hip_bf16.h>
#include <math.h>

// Problem constants
#define BB 64
#define SS 2048
#define HH 1024
#define EE 1024
#define DD 64          // window half-size
#define G4H 4096       // 4*H
#define KS1 16         // k-splits for gates GEMM (K=3072, kchunk=192) -> 1024 blocks, 4/CU
#define KS2 16         // k-splits for the H=1024 GEMMs (kchunk=64)

typedef __attribute__((ext_vector_type(8))) short short8;
typedef __attribute__((ext_vector_type(4))) float floatx4;

#define MFMA_BF16(a, b, c) __builtin_amdgcn_mfma_f32_16x16x32_bf16((a), (b), (c), 0, 0, 0)

__device__ __forceinline__ float sigmoidf_(float x) { return 1.0f / (1.0f + expf(-x)); }

__device__ __forceinline__ ushort f2bf(float f) {
    return __builtin_bit_cast(ushort, __float2bfloat16(f));
}

// Truncation-based hi/lo bf16 split of a float4, stored to LDS (row stride 72 ushorts).
// hi = top 16 bits (trunc, bit-ops only); lo = (v - hi) rounded to bf16.
// Error: hi+lo representation ~2^-17 rel; missing lo*lo term in products ~2^-16 rel.
__device__ __forceinline__ void stage_split(ushort* hbase, ushort* lbase, int row, int col, float4 v) {
    const uint bx = __float_as_uint(v.x), by = __float_as_uint(v.y);
    const uint bz = __float_as_uint(v.z), bw = __float_as_uint(v.w);
    uint2 hp;
    hp.x = (bx >> 16) | (by & 0xffff0000u);
    hp.y = (bz >> 16) | (bw & 0xffff0000u);
    const float lx = v.x - __uint_as_float(bx & 0xffff0000u);
    const float ly = v.y - __uint_as_float(by & 0xffff0000u);
    const float lz = v.z - __uint_as_float(bz & 0xffff0000u);
    const float lw = v.w - __uint_as_float(bw & 0xffff0000u);
    uint2 lp;
    lp.x = (uint)f2bf(lx) | ((uint)f2bf(ly) << 16);
    lp.y = (uint)f2bf(lz) | ((uint)f2bf(lw) << 16);
    *(uint2*)(hbase + row * 72 + col) = hp;
    *(uint2*)(lbase + row * 72 + col) = lp;
}

// bf16x3 split-MFMA partial GEMM: partial = sum_{k in chunk} Xrow(b,k)*Wrow(j,k)
// X/W are each a concat of two row-major matrices along k (split at k1len).
// Tile: 64 j x 64 b x 64 k. 4 waves; wave w owns j-subtile w. grid=(Jtot/64, KS), block=256.
// STORE_BJ=false: part[ks][j][b] (scalar stores). STORE_BJ=true: part[ks][b][j] (float4 stores).
template<bool STORE_BJ>
__global__ __launch_bounds__(256) void gemm_mfma(
    const float* __restrict__ X1, int x1ld,
    const float* __restrict__ X2, int x2ld,
    const float* __restrict__ W1, int w1ld,
    const float* __restrict__ W2, int w2ld,
    int k1len, int Ktot, int Jtot,
    float* __restrict__ part)
{
    const int jt = blockIdx.x;
    const int ks = blockIdx.y;
    const int KS = gridDim.y;
    const int kchunk = Ktot / KS;
    const int k0 = ks * kchunk;
    const int t  = threadIdx.x;

    const int c = t & 15;
    const int r = t >> 4;
    const int lane = t & 63;
    const int wj   = t >> 6;
    const int rr   = lane & 15;
    const int kg   = lane >> 4;

    __shared__ __align__(16) ushort Wh[64][72];
    __shared__ __align__(16) ushort Wl[64][72];
    __shared__ __align__(16) ushort Xh[64][72];
    __shared__ __align__(16) ushort Xl[64][72];

    floatx4 acc[4];
#pragma unroll
    for (int bs = 0; bs < 4; ++bs) acc[bs] = (floatx4){0.f, 0.f, 0.f, 0.f};

    for (int kk = k0; kk < k0 + kchunk; kk += 64) {
        const int kg4 = kk + 4 * c;
#pragma unroll
        for (int i = 0; i < 4; ++i) {
            const int row = r + 16 * i;
            const float* xs = (kg4 < k1len) ? (X1 + (size_t)row * x1ld + kg4)
                                            : (X2 + (size_t)row * x2ld + (kg4 - k1len));
            float4 xv = *(const float4*)xs;
            const int j = jt * 64 + row;
            const float* wsrc = (kg4 < k1len) ? (W1 + (size_t)j * w1ld + kg4)
                                              : (W2 + (size_t)j * w2ld + (kg4 - k1len));
            float4 wv = *(const float4*)wsrc;
            stage_split(&Xh[0][0], &Xl[0][0], row, 4 * c, xv);
            stage_split(&Wh[0][0], &Wl[0][0], row, 4 * c, wv);
        }
        __syncthreads();

        const int aoff = (wj * 16 + rr) * 72 + kg * 8;
        short8 ah[2], al[2];
        ah[0] = *(const short8*)((const void*)(&Wh[0][0] + aoff));
        ah[1] = *(const short8*)((const void*)(&Wh[0][0] + aoff + 32));
        al[0] = *(const short8*)((const void*)(&Wl[0][0] + aoff));
        al[1] = *(const short8*)((const void*)(&Wl[0][0] + aoff + 32));

#pragma unroll
        for (int bs = 0; bs < 4; ++bs) {
            const int boff = (bs * 16 + rr) * 72 + kg * 8;
#pragma unroll
            for (int kh = 0; kh < 2; ++kh) {
                short8 bh = *(const short8*)((const void*)(&Xh[0][0] + boff + kh * 32));
                short8 bl = *(const short8*)((const void*)(&Xl[0][0] + boff + kh * 32));
                acc[bs] = MFMA_BF16(ah[kh], bh, acc[bs]);   // hi*hi
                acc[bs] = MFMA_BF16(al[kh], bh, acc[bs]);   // lo*hi
                acc[bs] = MFMA_BF16(ah[kh], bl, acc[bs]);   // hi*lo
            }
        }
        __syncthreads();
    }

    // C/D layout: col = lane&15 (b within subtile), row = (lane>>4)*4 + reg (j within subtile)
    if (STORE_BJ) {
        const int j0 = jt * 64 + wj * 16 + kg * 4;
#pragma unroll
        for (int bs = 0; bs < 4; ++bs) {
            const int b = bs * 16 + rr;
            *(float4*)&part[((size_t)ks * BB + b) * Jtot + j0] =
                (float4){acc[bs][0], acc[bs][1], acc[bs][2], acc[bs][3]};
        }
    } else {
#pragma unroll
        for (int bs = 0; bs < 4; ++bs) {
#pragma unroll
            for (int reg = 0; reg < 4; ++reg) {
                const int j = jt * 64 + wj * 16 + kg * 4 + reg;
                const int b = bs * 16 + rr;
                part[((size_t)ks * Jtot + j) * BB + b] = acc[bs][reg];
            }
        }
    }
}

// LSTM cell from gate partials (layout [ks][j][b]). grid = H/4 = 256 blocks, block = 256.
__global__ __launch_bounds__(256) void lstm_cell(
    const float* __restrict__ part,
    const float* __restrict__ b_ih, const float* __restrict__ b_hh,
    const float* __restrict__ c0, float* __restrict__ yt)
{
    const int t = threadIdx.x;
    const int b = t & 63;
    const int h = blockIdx.x * 4 + (t >> 6);

    float g4[4];
#pragma unroll
    for (int q = 0; q < 4; ++q) {
        const int j = h + q * HH;
        float s = b_ih[j] + b_hh[j];
#pragma unroll
        for (int ks = 0; ks < KS1; ++ks)
            s += part[((size_t)ks * G4H + j) * BB + b];
        g4[q] = s;
    }
    const float ig = sigmoidf_(g4[0]);
    const float fg = sigmoidf_(g4[1]);
    const float gg = tanhf(g4[2]);
    const float og = sigmoidf_(g4[3]);
    const float c  = fg * c0[(size_t)b * HH + h] + ig * gg;
    yt[(size_t)b * HH + h] = og * tanhf(c);
}

// p_t = len * sigmoid( sum_i tanh(t1[b][i]) * v[i] ); window bounds.
// part2 layout [ks][b][i] -> coalesced float4 reads. grid = B, block = 256.
__global__ __launch_bounds__(256) void pos_kernel(
    const float* __restrict__ part2, const float* __restrict__ v,
    const int* __restrict__ elen,
    float* __restrict__ p_out, int* __restrict__ lr_out)
{
    const int b = blockIdx.x;
    const int t = threadIdx.x;

    float4 s = {0.f, 0.f, 0.f, 0.f};
#pragma unroll
    for (int ks = 0; ks < KS2; ++ks) {
        float4 pv = *(const float4*)&part2[((size_t)ks * BB + b) * HH + t * 4];
        s.x += pv.x; s.y += pv.y; s.z += pv.z; s.w += pv.w;
    }
    const float4 vv = *(const float4*)&v[t * 4];
    float acc = tanhf(s.x) * vv.x + tanhf(s.y) * vv.y
              + tanhf(s.z) * vv.z + tanhf(s.w) * vv.w;

    __shared__ float red[256];
    red[t] = acc;
    __syncthreads();
    if (t < 128) red[t] += red[t + 128];
    __syncthreads();
    if (t < 64) {
        float x = red[t] + red[t + 64];
#pragma unroll
        for (int off = 32; off; off >>= 1) x += __shfl_xor(x, off);
        if (t == 0) {
            const float pt  = sigmoidf_(x);
            const float len = (float)elen[b];
            const float p   = len * pt;
            const int   pf  = (int)floorf(p);
            const int   left  = max(0, pf - DD);
            const int   right = min(elen[b], pf + DD);
            p_out[b] = p;
            lr_out[b * 2 + 0] = left;
            lr_out[b * 2 + 1] = right;
        }
    }
}

// Windowed raw scores. grid = (B, 16), block = 256 (4 waves, 2 si each).
// Writes sc[b][0..128) with -1e30 padding beyond window.
__global__ __launch_bounds__(256) void attn_scores(
    const float* __restrict__ encode_h, const float* __restrict__ yt,
    const int* __restrict__ lr, float* __restrict__ sc_out)
{
    const int b = blockIdx.x;
    const int q = blockIdx.y;
    const int t = threadIdx.x;
    const int lane = t & 63;
    const int wv = t >> 6;

    __shared__ float yts[HH];
    *(float4*)&yts[t * 4] = *(const float4*)&yt[(size_t)b * HH + t * 4];
    const int left = lr[b * 2], right = lr[b * 2 + 1];
    const int wsize = right - left;
    __syncthreads();

#pragma unroll
    for (int rr = 0; rr < 2; ++rr) {
        const int si = q * 8 + wv * 2 + rr;
        float s = -1e30f;
        if (si < wsize) {
            const float* eh = encode_h + ((size_t)b * SS + (left + si)) * HH;
            s = 0.0f;
#pragma unroll
            for (int cc = 0; cc < 4; ++cc) {
                const int hb = cc * 256 + lane * 4;
                float4 e = *(const float4*)(eh + hb);
                s += e.x * yts[hb] + e.y * yts[hb + 1] + e.z * yts[hb + 2] + e.w * yts[hb + 3];
            }
#pragma unroll
            for (int off = 32; off; off >>= 1) s += __shfl_xor(s, off);
        }
        if (lane == 0) sc_out[b * 2 * DD + si] = s;
    }
}

// Fused softmax+gauss+ct: grid = (B, 8), block = 512 = 4 si-quarters x 128 h.
__global__ __launch_bounds__(512) void attn_ct(
    const float* __restrict__ encode_h, const float* __restrict__ sc,
    const float* __restrict__ p_buf, const int* __restrict__ lr,
    float* __restrict__ ct)
{
    const int b = blockIdx.x;
    const int t = threadIdx.x;
    const int lane = t & 63;
    const int hh = t & 127;          // h within 128-chunk
    const int q  = t >> 7;           // si-quarter 0..3
    const int h = blockIdx.y * 128 + hh;

    __shared__ float scs[2 * DD];
    __shared__ float ats[2 * DD];
    __shared__ float red[4][128];

    const int left = lr[b * 2];
    if (t < 2 * DD) scs[t] = sc[b * 2 * DD + t];
    __syncthreads();

    float m = fmaxf(scs[lane], scs[lane + 64]);
#pragma unroll
    for (int off = 32; off; off >>= 1) m = fmaxf(m, __shfl_xor(m, off));
    float ssum = expf(scs[lane] - m) + expf(scs[lane + 64] - m);
#pragma unroll
    for (int off = 32; off; off >>= 1) ssum += __shfl_xor(ssum, off);
    const float inv = 1.0f / ssum;

    if (t < 2 * DD) {
        const float dj = (float)(left + t) - p_buf[b];
        ats[t] = expf(scs[t] - m) * inv * expf(-(dj * dj) * (1.0f / 2048.0f));
    }
    __syncthreads();

    const float* ehb = encode_h + ((size_t)b * SS + left + q * 32) * HH + h;
    const float* atp = &ats[q * 32];
    float a0 = 0, a1 = 0, a2 = 0, a3 = 0, a4 = 0, a5 = 0, a6 = 0, a7 = 0;
#pragma unroll
    for (int si = 0; si < 32; si += 8) {
        a0 = fmaf(atp[si + 0], ehb[(size_t)(si + 0) * HH], a0);
        a1 = fmaf(atp[si + 1], ehb[(size_t)(si + 1) * HH], a1);
        a2 = fmaf(atp[si + 2], ehb[(size_t)(si + 2) * HH], a2);
        a3 = fmaf(atp[si + 3], ehb[(size_t)(si + 3) * HH], a3);
        a4 = fmaf(atp[si + 4], ehb[(size_t)(si + 4) * HH], a4);
        a5 = fmaf(atp[si + 5], ehb[(size_t)(si + 5) * HH], a5);
        a6 = fmaf(atp[si + 6], ehb[(size_t)(si + 6) * HH], a6);
        a7 = fmaf(atp[si + 7], ehb[(size_t)(si + 7) * HH], a7);
    }
    const float a = ((a0 + a1) + (a2 + a3)) + ((a4 + a5) + (a6 + a7));

    if (q != 0) red[q][hh] = a;
    __syncthreads();
    if (q == 0)
        ct[(size_t)b * HH + h] = (a + red[1][hh]) + (red[2][hh] + red[3][hh]);
}

// out[b][j] = sum_ks part3[ks][j][b].  grid = H/4 = 256, block = 256 (coalesced reads).
__global__ __launch_bounds__(256) void reduce_out(
    const float* __restrict__ part3, float* __restrict__ out)
{
    const int t = threadIdx.x;
    const int b = t & 63;
    const int j = blockIdx.x * 4 + (t >> 6);
    float s = 0.0f;
#pragma unroll
    for (int ks = 0; ks < KS2; ++ks)
        s += part3[((size_t)ks * HH + j) * BB + b];
    out[(size_t)b * HH + j] = s;
}

extern "C" void kernel_launch(void* const* d_in, const int* in_sizes, int n_in,
                              void* d_out, int out_size, void* d_ws, size_t ws_size,
                              hipStream_t stream)
{
    const float* encode_h = (const float*)d_in[0];
    const float* x_t      = (const float*)d_in[1];
    const float* h0       = (const float*)d_in[2];
    const float* c0       = (const float*)d_in[3];
    const float* W_ih     = (const float*)d_in[4];
    const float* W_hh     = (const float*)d_in[5];
    const float* b_ih     = (const float*)d_in[6];
    const float* b_hh     = (const float*)d_in[7];
    const float* W_ht2tan = (const float*)d_in[8];
    const float* W_tan2pt = (const float*)d_in[9];
    const float* W_ct2ht  = (const float*)d_in[10];
    const int*   elen     = (const int*)d_in[11];
    float* out = (float*)d_out;

    float* ws = (float*)d_ws;
    float* gates_part = ws;                                   // KS1*4096*64 = 4M floats
    float* yt    = gates_part + (size_t)KS1 * G4H * BB;       // 65536
    float* part2 = yt + (size_t)BB * HH;                      // KS2*1024*64 = 1M
    float* pbuf  = part2 + (size_t)KS2 * HH * BB;             // 64
    int*   lrbuf = (int*)(pbuf + BB);                         // 128 ints
    float* scbuf = pbuf + BB + 2 * BB;                        // 64*128
    float* ctbuf = scbuf + (size_t)BB * 2 * DD;               // 65536
    float* part3 = ctbuf + (size_t)BB * HH;                   // KS2*1024*64 = 1M

    // K1: gates partial GEMM (K = 2048 | 1024 concat), grid (64,16) = 1024 blocks (4/CU)
    dim3 g1(G4H / 64, KS1);
    gemm_mfma<false><<<g1, 256, 0, stream>>>(x_t, EE + HH, h0, HH,
                                             W_ih, EE + HH, W_hh, HH,
                                             2048, 3072, G4H, gates_part);
    // K2: LSTM cell -> yt
    lstm_cell<<<HH / 4, 256, 0, stream>>>(gates_part, b_ih, b_hh, c0, yt);

    // K3a: t1 = yt @ W_ht2tan^T (partials, [ks][b][j] layout), grid (16,16) = 256 blocks
    dim3 g3(HH / 64, KS2);
    gemm_mfma<true><<<g3, 256, 0, stream>>>(yt, HH, yt, HH,
                                            W_ht2tan, HH, W_ht2tan, HH,
                                            HH, HH, HH, part2);
    // K3b: p, window bounds (coalesced float4 reads of part2)
    pos_kernel<<<BB, 256, 0, stream>>>(part2, W_tan2pt, elen, pbuf, lrbuf);

    // K4a: windowed raw scores, grid (64,16) = 1024 blocks (2 si per wave)
    dim3 g4a(BB, 16);
    attn_scores<<<g4a, 256, 0, stream>>>(encode_h, yt, lrbuf, scbuf);
    // K4b: softmax + gauss + ct, grid (64,8) = 512 blocks, block 512
    dim3 g4b(BB, 8);
    attn_ct<<<g4b, 512, 0, stream>>>(encode_h, scbuf, pbuf, lrbuf, ctbuf);

    // K5: ht partials = ct @ W_ct2ht^T, grid (16,16), [ks][j][b] layout
    gemm_mfma<false><<<g3, 256, 0, stream>>>(ctbuf, HH, ctbuf, HH,
                                             W_ct2ht, HH, W_ct2ht, HH,
                                             HH, HH, HH, part3);
    // K6: reduce -> out
    reduce_out<<<HH / 4, 256, 0, stream>>>(part3, out);
}